// Round 6
// baseline (730.387 us; speedup 1.0000x reference)
//
#include <hip/hip_runtime.h>
#include <hip/hip_cooperative_groups.h>
#include <cstdint>
#include <cstddef>

namespace cg = cooperative_groups;

// Problem constants (fixed by the reference)
#define N_NODES 10000
#define F_IN    512
#define NHID    32
#define LATENT  16

typedef float v4f __attribute__((ext_vector_type(4)));

// Scratch layout inside d_out's adjacency region (decoder overwrites it last).
#define OF_H0   0              // [N,32] f32
#define OF_H    320000         // [N,32] f32

__device__ __forceinline__ float sigmoid_fast(float x) {
    return __builtin_amdgcn_rcpf(1.0f + __expf(-x));
}

// ===========================================================================
// Cooperative mega-kernel (conservative occupancy: 512 blocks, 16 KB LDS,
// VGPR<=128 via launch_bounds(256,4) -> runtime coop check passes easily).
// ===========================================================================
#define CGRID     512
#define CG1_TILES 313          // gemm1 row-tiles of 32 rows
#define CG1_KC    128          // W1 k-chunk in LDS (16 KB)

__global__ __launch_bounds__(256, 4) void gae_mega_kernel(
    const float* __restrict__ x, const float* __restrict__ W1,
    const float* __restrict__ W2, const int* __restrict__ src,
    const int* __restrict__ dst, const float* __restrict__ ew,
    float* __restrict__ out, float* __restrict__ zv,
    float* __restrict__ h0, float* __restrict__ h, int E) {
    cg::grid_group grid = cg::this_grid();
    __shared__ float smem[CG1_KC * NHID];  // 16 KB; reused for W2 in phase C

    const int b   = blockIdx.x;
    const int tid = threadIdx.x;

    // ---------------- Phase A: gemm1 (b<313) | zero h,z (b>=313) ----------
    if (b < CG1_TILES) {
        const int row0 = b * 32;
        const int rp   = tid >> 3;
        const int cg_  = (tid & 7) * 4;
        const int gr   = min(row0 + rp, N_NODES - 1);
        const float4* __restrict__ xrow = (const float4*)(x + (size_t)gr * F_IN);

        float4 acc = make_float4(0.f, 0.f, 0.f, 0.f);
        for (int kc = 0; kc < F_IN; kc += CG1_KC) {
            {
                const float4* __restrict__ wg = (const float4*)(W1 + (size_t)kc * NHID);
                float4* __restrict__ ws4 = (float4*)smem;
                const int base = tid * 4;   // 1024 float4 total / 256 thr
#pragma unroll
                for (int i = 0; i < 4; ++i) ws4[base + i] = wg[base + i];
            }
            __syncthreads();
            const int k4base = kc >> 2;
#pragma unroll 4
            for (int kk4 = 0; kk4 < CG1_KC / 4; ++kk4) {
                const float4 xv = xrow[k4base + kk4];
                const float4 w0 = *(const float4*)&smem[(kk4 * 4 + 0) * NHID + cg_];
                const float4 w1 = *(const float4*)&smem[(kk4 * 4 + 1) * NHID + cg_];
                const float4 w2 = *(const float4*)&smem[(kk4 * 4 + 2) * NHID + cg_];
                const float4 w3 = *(const float4*)&smem[(kk4 * 4 + 3) * NHID + cg_];
                acc.x += xv.x * w0.x + xv.y * w1.x + xv.z * w2.x + xv.w * w3.x;
                acc.y += xv.x * w0.y + xv.y * w1.y + xv.z * w2.y + xv.w * w3.y;
                acc.z += xv.x * w0.z + xv.y * w1.z + xv.z * w2.z + xv.w * w3.z;
                acc.w += xv.x * w0.w + xv.y * w1.w + xv.z * w2.w + xv.w * w3.w;
            }
            __syncthreads();
        }
        if (row0 + rp < N_NODES)
            *(float4*)&h0[(size_t)(row0 + rp) * NHID + cg_] = acc;
    } else {
        const int t    = (b - CG1_TILES) * 256 + tid;
        const int nthr = (CGRID - CG1_TILES) * 256;
        const v4f zero = {0.f, 0.f, 0.f, 0.f};
        for (int i = t; i < (N_NODES * NHID) / 4; i += nthr)
            *(v4f*)&((float4*)h)[i] = zero;
        for (int i = t; i < (N_NODES * LATENT) / 4; i += nthr)
            *(v4f*)&((float4*)zv)[i] = zero;
    }
    grid.sync();

    // ---------------- Phase B: h = A @ h0 (scatter, D=32) ------------------
    {
        const int total  = E * NHID;
        const int stride = CGRID * 256;
        for (int idx = b * 256 + tid; idx < total; idx += stride) {
            const int e = idx >> 5;
            const int d = idx & 31;
            const float val = ew[e] * h0[(size_t)src[e] * NHID + d];
            atomicAdd(&h[(size_t)dst[e] * NHID + d], val);
        }
    }
    grid.sync();

    // ---------------- Phase C: z = A @ (h @ W2) fused ----------------------
    {
        for (int t = tid; t < NHID * LATENT; t += 256) smem[t] = W2[t];
        __syncthreads();
        const int total  = E * LATENT;
        const int stride = CGRID * 256;
        for (int idx = b * 256 + tid; idx < total; idx += stride) {
            const int e = idx >> 4;
            const int d = idx & (LATENT - 1);
            const float4* __restrict__ hr = (const float4*)(h + (size_t)src[e] * NHID);
            float acc = 0.f;
#pragma unroll
            for (int k4 = 0; k4 < NHID / 4; ++k4) {
                const float4 hv = hr[k4];
                acc += hv.x * smem[(k4 * 4 + 0) * LATENT + d]
                     + hv.y * smem[(k4 * 4 + 1) * LATENT + d]
                     + hv.z * smem[(k4 * 4 + 2) * LATENT + d]
                     + hv.w * smem[(k4 * 4 + 3) * LATENT + d];
            }
            atomicAdd(&zv[(size_t)dst[e] * LATENT + d], ew[e] * acc);
        }
    }
    grid.sync();

    // ---------------- Phase D: decoder -------------------------------------
    // 500 active blocks: tx = b/50 -> j-stripe of 1024 cols; i-chunk of 200.
    if (b < 500) {
        const int tx = b / 50;
        const int i0 = (b % 50) * 200;
        const int j0 = tx * 1024 + tid * 4;
        if (j0 < N_NODES) {
            float4 zj[4][4];
            const float4* __restrict__ zp = (const float4*)(zv + (size_t)j0 * LATENT);
#pragma unroll
            for (int c = 0; c < 4; ++c)
#pragma unroll
                for (int q = 0; q < 4; ++q) zj[c][q] = zp[c * 4 + q];

            float* orow = out + (size_t)i0 * N_NODES + j0;
            const float* zrow = zv + (size_t)i0 * LATENT;
#pragma unroll 2
            for (int ii = 0; ii < 200; ++ii) {
                const float4* __restrict__ zi = (const float4*)(zrow + ii * LATENT);
                const float4 c0 = zi[0], c1 = zi[1], c2 = zi[2], c3 = zi[3];
                v4f r;
#pragma unroll
                for (int c = 0; c < 4; ++c) {
                    const float s =
                          c0.x * zj[c][0].x + c0.y * zj[c][0].y + c0.z * zj[c][0].z + c0.w * zj[c][0].w
                        + c1.x * zj[c][1].x + c1.y * zj[c][1].y + c1.z * zj[c][1].z + c1.w * zj[c][1].w
                        + c2.x * zj[c][2].x + c2.y * zj[c][2].y + c2.z * zj[c][2].z + c2.w * zj[c][2].w
                        + c3.x * zj[c][3].x + c3.y * zj[c][3].y + c3.z * zj[c][3].z + c3.w * zj[c][3].w;
                    r[c] = sigmoid_fast(s);
                }
                __builtin_nontemporal_store(r, (v4f*)orow);
                orow += N_NODES;
            }
        }
    }
}

// ===========================================================================
// Fallback path: verbatim round-4 four-dispatch pipeline (known-good 512 us).
// ===========================================================================
#define G1_TILES 313
#define ZERO_BLOCKS 64
#define G1_KC 256

__global__ __launch_bounds__(256) void stage1_kernel(const float* __restrict__ x,
                                                     const float* __restrict__ W1,
                                                     float* __restrict__ h0,
                                                     float* __restrict__ h,
                                                     float* __restrict__ z) {
    __shared__ float w1s[G1_KC * NHID];  // 32 KB

    if (blockIdx.x >= G1_TILES) {
        const int tid = (blockIdx.x - G1_TILES) * 256 + threadIdx.x;
        const int nthr = ZERO_BLOCKS * 256;
        const v4f zero = {0.f, 0.f, 0.f, 0.f};
        for (int i = tid; i < (N_NODES * NHID) / 4; i += nthr)
            *(v4f*)&((float4*)h)[i] = zero;
        for (int i = tid; i < (N_NODES * LATENT) / 4; i += nthr)
            *(v4f*)&((float4*)z)[i] = zero;
        return;
    }

    const int row0 = blockIdx.x * 32;
    const int rp   = threadIdx.x >> 3;
    const int cg_  = (threadIdx.x & 7) * 4;
    const int gr   = min(row0 + rp, N_NODES - 1);
    const float4* __restrict__ xrow = (const float4*)(x + (size_t)gr * F_IN);

    float4 acc = make_float4(0.f, 0.f, 0.f, 0.f);
    for (int kc = 0; kc < F_IN; kc += G1_KC) {
        {
            const float4* __restrict__ wg = (const float4*)(W1 + (size_t)kc * NHID);
            float4* __restrict__ ws4 = (float4*)w1s;
            const int b = threadIdx.x * 8;
#pragma unroll
            for (int i = 0; i < 8; ++i) ws4[b + i] = wg[b + i];
        }
        __syncthreads();
        const int k4base = kc >> 2;
#pragma unroll 4
        for (int kk4 = 0; kk4 < G1_KC / 4; ++kk4) {
            const float4 xv = xrow[k4base + kk4];
            const float4 w0 = *(const float4*)&w1s[(kk4 * 4 + 0) * NHID + cg_];
            const float4 w1 = *(const float4*)&w1s[(kk4 * 4 + 1) * NHID + cg_];
            const float4 w2 = *(const float4*)&w1s[(kk4 * 4 + 2) * NHID + cg_];
            const float4 w3 = *(const float4*)&w1s[(kk4 * 4 + 3) * NHID + cg_];
            acc.x += xv.x * w0.x + xv.y * w1.x + xv.z * w2.x + xv.w * w3.x;
            acc.y += xv.x * w0.y + xv.y * w1.y + xv.z * w2.y + xv.w * w3.y;
            acc.z += xv.x * w0.z + xv.y * w1.z + xv.z * w2.z + xv.w * w3.z;
            acc.w += xv.x * w0.w + xv.y * w1.w + xv.z * w2.w + xv.w * w3.w;
        }
        __syncthreads();
    }
    if (row0 + rp < N_NODES)
        *(float4*)&h0[(size_t)(row0 + rp) * NHID + cg_] = acc;
}

__global__ __launch_bounds__(256) void spmm32_kernel(const int* __restrict__ src,
                                                     const int* __restrict__ dst,
                                                     const float* __restrict__ w,
                                                     const float* __restrict__ hin,
                                                     float* __restrict__ hout,
                                                     int E) {
    const int idx = blockIdx.x * 256 + threadIdx.x;
    const int e = idx >> 5;
    const int d = idx & 31;
    if (e < E) {
        const float val = w[e] * hin[(size_t)src[e] * NHID + d];
        atomicAdd(&hout[(size_t)dst[e] * NHID + d], val);
    }
}

__global__ __launch_bounds__(256) void l2_fused_kernel(const int* __restrict__ src,
                                                       const int* __restrict__ dst,
                                                       const float* __restrict__ w,
                                                       const float* __restrict__ h,
                                                       const float* __restrict__ W2,
                                                       float* __restrict__ z,
                                                       int E) {
    __shared__ float w2s[NHID * LATENT];
    for (int t = threadIdx.x; t < NHID * LATENT; t += 256) w2s[t] = W2[t];
    __syncthreads();

    const int idx = blockIdx.x * 256 + threadIdx.x;
    const int e = idx >> 4;
    const int d = idx & (LATENT - 1);
    if (e < E) {
        const float4* __restrict__ hr = (const float4*)(h + (size_t)src[e] * NHID);
        float acc = 0.f;
#pragma unroll
        for (int k4 = 0; k4 < NHID / 4; ++k4) {
            const float4 hv = hr[k4];
            acc += hv.x * w2s[(k4 * 4 + 0) * LATENT + d]
                 + hv.y * w2s[(k4 * 4 + 1) * LATENT + d]
                 + hv.z * w2s[(k4 * 4 + 2) * LATENT + d]
                 + hv.w * w2s[(k4 * 4 + 3) * LATENT + d];
        }
        atomicAdd(&z[(size_t)dst[e] * LATENT + d], w[e] * acc);
    }
}

#define TI 40
__global__ __launch_bounds__(256) void decoder_kernel(const float* __restrict__ z,
                                                      float* __restrict__ out) {
    const int j0 = (blockIdx.x * 256 + threadIdx.x) * 4;
    const int i0 = blockIdx.y * TI;
    if (j0 >= N_NODES) return;

    float4 zj[4][4];
    {
        const float4* __restrict__ zp = (const float4*)(z + (size_t)j0 * LATENT);
#pragma unroll
        for (int c = 0; c < 4; ++c)
#pragma unroll
            for (int q = 0; q < 4; ++q) zj[c][q] = zp[c * 4 + q];
    }
#pragma unroll 2
    for (int ii = 0; ii < TI; ++ii) {
        const int i = i0 + ii;
        const float4* __restrict__ zi = (const float4*)(z + (size_t)i * LATENT);
        const float4 c0 = zi[0], c1 = zi[1], c2 = zi[2], c3 = zi[3];
        v4f r;
#pragma unroll
        for (int c = 0; c < 4; ++c) {
            const float s =
                  c0.x * zj[c][0].x + c0.y * zj[c][0].y + c0.z * zj[c][0].z + c0.w * zj[c][0].w
                + c1.x * zj[c][1].x + c1.y * zj[c][1].y + c1.z * zj[c][1].z + c1.w * zj[c][1].w
                + c2.x * zj[c][2].x + c2.y * zj[c][2].y + c2.z * zj[c][2].z + c2.w * zj[c][2].w
                + c3.x * zj[c][3].x + c3.y * zj[c][3].y + c3.z * zj[c][3].z + c3.w * zj[c][3].w;
            r[c] = sigmoid_fast(s);
        }
        __builtin_nontemporal_store(r, (v4f*)(out + (size_t)i * N_NODES + j0));
    }
}

// ---------------------------------------------------------------------------
extern "C" void kernel_launch(void* const* d_in, const int* in_sizes, int n_in,
                              void* d_out, int out_size, void* d_ws, size_t ws_size,
                              hipStream_t stream) {
    const float* x  = (const float*)d_in[0];
    const float* W1 = (const float*)d_in[1];
    const float* W2 = (const float*)d_in[2];
    const int*   ei = (const int*)d_in[3];
    const float* ew = (const float*)d_in[4];
    int E = in_sizes[3] / 2;
    const int* src = ei;
    const int* dst = ei + E;

    float* out = (float*)d_out;
    float* zv  = out + (size_t)N_NODES * N_NODES;
    float* h0  = out + OF_H0;
    float* h   = out + OF_H;

    void* args[] = {(void*)&x, (void*)&W1, (void*)&W2, (void*)&src, (void*)&dst,
                    (void*)&ew, (void*)&out, (void*)&zv, (void*)&h0, (void*)&h,
                    (void*)&E};
    hipError_t err = hipLaunchCooperativeKernel((const void*)gae_mega_kernel,
                                                dim3(CGRID), dim3(256), args, 0,
                                                stream);
    if (err != hipSuccess) {
        (void)hipGetLastError();  // clear sticky error, take the 4-dispatch path
        stage1_kernel<<<G1_TILES + ZERO_BLOCKS, 256, 0, stream>>>(x, W1, h0, h, zv);
        spmm32_kernel<<<(E * NHID + 255) / 256, 256, 0, stream>>>(src, dst, ew, h0, h, E);
        l2_fused_kernel<<<(E * LATENT + 255) / 256, 256, 0, stream>>>(src, dst, ew, h, W2, zv, E);
        dim3 dgrid((N_NODES / 4 + 255) / 256, N_NODES / TI);
        decoder_kernel<<<dgrid, 256, 0, stream>>>(zv, out);
    }
}